// Round 10
// baseline (93.339 us; speedup 1.0000x reference)
//
#include <hip/hip_runtime.h>

// AAConv: 3x3 conv (256->256) + 1x1 conv (256->768 kqv) + 8-head attention
// (HW=1024, DKH=DVH=32), out = concat([conv_out, attn_out]) (8,512,32,32) fp32.
//
// R14: conv split by co-QUARTERS (2h x 64co per block) -> grid 1024
//   (512 conv + 512 attn) = 4 blocks/CU, 16 waves/CU (was 12), per-CU mix
//   {2 conv : 2 attn} (balanced drain). Unlike R8's h-split, the co-split
//   keeps per-XCD WcT traffic constant (294KB x 64 blk = 18.9MB/XCD, same
//   as R9); only xT halo doubles (+2MB/XCD). Wave tile 32co x 32n (acc 2x2),
//   same 2:1 MFMA:ds ratio, Xc staging/swizzle identical.
// attn/kqv/prep identical to R13.
//
// ws layout (bytes): vB @0 (4,194,304) | kT @4,194,304 (4,194,304)
//   | qT @8,388,608 (4,194,304) | xT @12,582,912 (4,194,304)
//   | WcT @16,777,216 (1,179,648) | WaT @17,956,864 (393,216)

typedef __attribute__((ext_vector_type(8))) short short8;
typedef __attribute__((ext_vector_type(4))) float f32x4;
typedef __attribute__((ext_vector_type(16))) float f32x16;
typedef unsigned short u16;

// 1/sqrt(32) * log2(e): Q pre-scale folding softmax into exp2 domain.
#define QSCALE 0.25503487629898483f

__device__ inline u16 f2bf(float f) {
  unsigned u = __builtin_bit_cast(unsigned, f);
  return (u16)((u + 0x7FFFu + ((u >> 16) & 1u)) >> 16);
}
__device__ inline unsigned pack2bf(float a, float b) {
  return (unsigned)f2bf(a) | ((unsigned)f2bf(b) << 16);
}
// pack two f32 -> two bf16 (round-half-up) in one perm.
__device__ inline unsigned packP(float a, float b) {
  unsigned au = __builtin_bit_cast(unsigned, a) + 0x8000u;
  unsigned bu = __builtin_bit_cast(unsigned, b) + 0x8000u;
  return __builtin_amdgcn_perm(bu, au, 0x07060302u);
}

// ---------------------------------------------------------------------------
// prep: grid 320. xT path uses packP (pairwise) for the bf16 convert.
// ---------------------------------------------------------------------------
__global__ __launch_bounds__(256) void prep_kernel(const float* __restrict__ x,
                                                   const float* __restrict__ cw,
                                                   const float* __restrict__ aw,
                                                   u16* __restrict__ xT,
                                                   u16* __restrict__ WcT,
                                                   u16* __restrict__ WaT) {
  __shared__ float T[64][65];
  int bid = blockIdx.x, tid = threadIdx.x;

  if (bid < 128) {
    int b = bid >> 4, n0 = (bid & 15) * 64;
#pragma unroll
    for (int rep = 0; rep < 2; ++rep) {
      int flat = rep * 256 + tid;          // 0..511
      int n = flat & 63, cg = flat >> 6;   // cg 0..7 -> 32 ci each
      const float* xs = x + b * 256 * 1024 + n0 + n;
#pragma unroll
      for (int q = 0; q < 4; ++q) {
        uint4 pk;
#pragma unroll
        for (int jj = 0; jj < 4; ++jj) {
          float a = xs[(cg * 32 + q * 8 + 2 * jj) * 1024];
          float c = xs[(cg * 32 + q * 8 + 2 * jj + 1) * 1024];
          ((unsigned*)&pk)[jj] = packP(a, c);
        }
        *(uint4*)&xT[(b * 1024 + n0 + n) * 256 + cg * 32 + q * 8] = pk;
      }
    }
    return;
  }

  int tt = bid - 128;
  int chunk = tt >> 4, t = tt & 15;
  int ci0 = (t & 3) * 64, r0 = (t >> 2) * 64;
  bool isconv = chunk < 9;
  float scale = (chunk == 10) ? QSCALE : 1.0f;

#pragma unroll
  for (int rep = 0; rep < 16; ++rep) {
    int flat = rep * 256 + tid;
    int i = flat >> 6, j = flat & 63;     // i = ci-local, j = dst-row-local
    T[i][j] = isconv ? cw[(chunk * 256 + ci0 + i) * 256 + r0 + j]
                     : aw[(ci0 + i) * 768 + (chunk - 9) * 256 + r0 + j];
  }
  __syncthreads();
#pragma unroll
  for (int rep = 0; rep < 4; ++rep) {
    int flat = rep * 256 + tid;
    int jj = flat >> 4, qq = flat & 15;   // dst row r0+jj, ci ci0+qq*4
    float v0 = T[qq * 4 + 0][jj] * scale;
    float v1 = T[qq * 4 + 1][jj] * scale;
    float v2 = T[qq * 4 + 2][jj] * scale;
    float v3 = T[qq * 4 + 3][jj] * scale;
    uint2 pk = {pack2bf(v0, v1), pack2bf(v2, v3)};
    if (isconv)
      *(uint2*)&WcT[(chunk * 256 + r0 + jj) * 256 + ci0 + qq * 4] = pk;
    else
      *(uint2*)&WaT[((chunk - 9) * 256 + r0 + jj) * 256 + ci0 + qq * 4] = pk;
  }
}

// ---------------------------------------------------------------------------
// kqv: GEMM [768x256]x[256x1024] per batch. grid 768. b = bid&7 (XCD-local).
// R12: LDS-staged K-step tiles, double-buffered, 2-step register prefetch.
// ---------------------------------------------------------------------------
__global__ __launch_bounds__(256) void kqv_kernel(const u16* __restrict__ xT,
                                                  const u16* __restrict__ WaT,
                                                  const float* __restrict__ ab,
                                                  u16* __restrict__ kT,
                                                  u16* __restrict__ qT,
                                                  u16* __restrict__ vB) {
  __shared__ __align__(16) u16 S[15360];      // 30 KB: 2 x (A 5120 + B 2560)
  int bid = blockIdx.x;
  int b = bid & 7, idx = bid >> 3;       // XCD-local batch
  int ot = idx >> 4, nt = idx & 15;      // idx 0..95 -> ot 0..5, nt 0..15
  int tid = threadIdx.x, wave = tid >> 6, lane = tid & 63;
  int ln = lane & 15, g = lane >> 4;
  int o0 = ot * 128 + (wave & 1) * 64;
  int n0 = nt * 64 + (wave >> 1) * 32;
  const u16* xb = xT + b * 1024 * 256;

  // staging coords: row rA (0..63 for B, rA and rA+64 for A), 16B slot slA
  int rA = tid >> 2, slA = tid & 3;
  const u16* aS0 = WaT + (ot * 128 + rA) * 256 + slA * 8;
  const u16* aS1 = aS0 + 64 * 256;
  const u16* bS = xb + (nt * 64 + rA) * 256 + slA * 8;
  int aD0 = rA * 40 + slA * 8;
  int aD1 = aD0 + 64 * 40;
  int bD = 5120 + rA * 40 + slA * 8;

  // per-wave fragment LDS offsets
  int aF = ((wave & 1) * 64 + ln) * 40 + g * 8;
  int bF = 5120 + ((wave >> 1) * 32 + ln) * 40 + g * 8;

  f32x4 acc[4][2];
#pragma unroll
  for (int i = 0; i < 4; ++i)
#pragma unroll
    for (int j = 0; j < 2; ++j) acc[i][j] = (f32x4){0.f, 0.f, 0.f, 0.f};

  // prologue: stage step 0 into buf0; prefetch step 1 into regs
  *(short8*)&S[aD0] = *(const short8*)aS0;
  *(short8*)&S[aD1] = *(const short8*)aS1;
  *(short8*)&S[bD] = *(const short8*)bS;
  __syncthreads();
  short8 pa0 = *(const short8*)(aS0 + 32);
  short8 pa1 = *(const short8*)(aS1 + 32);
  short8 pb = *(const short8*)(bS + 32);

#pragma unroll
  for (int s = 0; s < 8; ++s) {
    const u16* buf = S + (s & 1) * 7680;
    short8 a0 = *(const short8*)&buf[aF];
    short8 a1 = *(const short8*)&buf[aF + 16 * 40];
    short8 a2 = *(const short8*)&buf[aF + 32 * 40];
    short8 a3 = *(const short8*)&buf[aF + 48 * 40];
    short8 b0 = *(const short8*)&buf[bF];
    short8 b1 = *(const short8*)&buf[bF + 16 * 40];
    acc[0][0] = __builtin_amdgcn_mfma_f32_16x16x32_bf16(a0, b0, acc[0][0], 0, 0, 0);
    acc[0][1] = __builtin_amdgcn_mfma_f32_16x16x32_bf16(a0, b1, acc[0][1], 0, 0, 0);
    acc[1][0] = __builtin_amdgcn_mfma_f32_16x16x32_bf16(a1, b0, acc[1][0], 0, 0, 0);
    acc[1][1] = __builtin_amdgcn_mfma_f32_16x16x32_bf16(a1, b1, acc[1][1], 0, 0, 0);
    acc[2][0] = __builtin_amdgcn_mfma_f32_16x16x32_bf16(a2, b0, acc[2][0], 0, 0, 0);
    acc[2][1] = __builtin_amdgcn_mfma_f32_16x16x32_bf16(a2, b1, acc[2][1], 0, 0, 0);
    acc[3][0] = __builtin_amdgcn_mfma_f32_16x16x32_bf16(a3, b0, acc[3][0], 0, 0, 0);
    acc[3][1] = __builtin_amdgcn_mfma_f32_16x16x32_bf16(a3, b1, acc[3][1], 0, 0, 0);
    if (s < 7) {
      u16* nb = S + ((s + 1) & 1) * 7680;
      *(short8*)&nb[aD0] = pa0;
      *(short8*)&nb[aD1] = pa1;
      *(short8*)&nb[bD] = pb;
      if (s < 6) {
        pa0 = *(const short8*)(aS0 + (s + 2) * 32);
        pa1 = *(const short8*)(aS1 + (s + 2) * 32);
        pb = *(const short8*)(bS + (s + 2) * 32);
      }
    }
    __syncthreads();
  }

  if (ot >= 4) {
    // V: natural [dv][m] layout, scalar bf16 stores.
#pragma unroll
    for (int it = 0; it < 4; ++it)
#pragma unroll
      for (int r = 0; r < 4; ++r) {
        int o = o0 + it * 16 + g * 4 + r;
        float bias = ab[o];
#pragma unroll
        for (int jt = 0; jt < 2; ++jt) {
          int n = n0 + jt * 16 + ln;
          vB[(b * 256 + (o - 512)) * 1024 + n] = f2bf(acc[it][jt][r] + bias);
        }
      }
    return;
  }

  // K/Q: transpose 128o x 64n tile via LDS (aliases S), write [b][h][n][d].
  u16* Tt = S;                              // [64][136]
  bool isQ = (ot >= 2);
  float bs = isQ ? QSCALE : 1.0f;
  int olb = (wave & 1) * 64;
  int nlb = (wave >> 1) * 32;
#pragma unroll
  for (int it = 0; it < 4; ++it)
#pragma unroll
    for (int jt = 0; jt < 2; ++jt) {
      int ol = olb + it * 16 + g * 4;
      int nl = nlb + jt * 16 + ln;
      int og = ot * 128 + ol;
      float v0 = acc[it][jt][0] + ab[og + 0] * bs;
      float v1 = acc[it][jt][1] + ab[og + 1] * bs;
      float v2 = acc[it][jt][2] + ab[og + 2] * bs;
      float v3 = acc[it][jt][3] + ab[og + 3] * bs;
      uint2 pk = {pack2bf(v0, v1), pack2bf(v2, v3)};
      *(uint2*)&Tt[nl * 136 + ol] = pk;
    }
  __syncthreads();
  u16* dst = isQ ? qT : kT;
#pragma unroll
  for (int rep = 0; rep < 4; ++rep) {
    int flat = rep * 256 + tid;
    int o8 = flat & 15, nl = flat >> 4;
    short8 v = *(const short8*)&Tt[nl * 136 + o8 * 8];
    int og256 = (ot & 1) * 128 + o8 * 8;   // o within the 256-row K (or Q) range
    int hh = og256 >> 5, d0 = og256 & 31;
    int ng = nt * 64 + nl;
    *(short8*)&dst[((b * 8 + hh) * 1024 + ng) * 32 + d0] = v;
  }
}

// ---------------------------------------------------------------------------
// FUSED conv + attn. grid 1024. b = bid&7; sub = bid>>3 (0..127);
// path = sub&1 (1 = conv), idx = sub>>1 (0..63).
//   conv: hp = idx>>2 (2 h-rows), coq = idx&3 (64-co quarter);
//         wave tile 32co x 32n: co += (wave&1)*32, nh = wave>>1 -> h0+nh.
//   attn: h = idx>>3, qt = idx&7 (128 q-rows, 4 waves x 32; R11 body).
// LDS union: conv Xc 4*34*72 u16 = 19.6KB; attn kv[2][4864] u16 = 19.0KB.
// ---------------------------------------------------------------------------
__global__ __launch_bounds__(256, 3) void conv_attn_kernel(
    const u16* __restrict__ xT, const u16* __restrict__ WcT,
    const float* __restrict__ cb, const u16* __restrict__ kT,
    const u16* __restrict__ qT, const u16* __restrict__ vB,
    float* __restrict__ out) {
  __shared__ __align__(16) unsigned char smem[19584];

  int bid = blockIdx.x;
  int b = bid & 7;                  // XCD-local batch
  int sub = bid >> 3;               // 0..127
  int path = sub & 1;
  int idx = sub >> 1;               // 0..63
  int tid = threadIdx.x;
  int wave = tid >> 6, lane = tid & 63;

  if (path == 1) {
    // ===== conv: 2 h-rows x 64 co per block; wave = 32co x 32n =====
    int ln = lane & 15, g = lane >> 4;
    u16* Xc = (u16*)smem;           // [4*34 rows][72], 19.6 KB
    int hp = idx >> 2, coq = idx & 3;
    int h0 = hp * 2;
    int co0 = coq * 64 + (wave & 1) * 32;
    int nh = wave >> 1;             // which of the 2 h-rows this wave owns

    f32x4 acc[2][2];
#pragma unroll
    for (int i = 0; i < 2; ++i)
#pragma unroll
      for (int j = 0; j < 2; ++j) acc[i][j] = (f32x4){0.f, 0.f, 0.f, 0.f};

    {
      int rp = tid >> 6, rest = tid & 63;
      int which = rest >> 5, cp = rest & 31;
      *(unsigned*)&Xc[(rp * 34 + which * 33) * 72 + cp * 2] = 0u;
    }

    for (int c0 = 0; c0 < 256; c0 += 64) {
      __syncthreads();
#pragma unroll
      for (int rep = 0; rep < 4; ++rep) {
        int flat = rep * 256 + tid;
        int cg = flat & 7, w = (flat >> 3) & 31, rp = flat >> 8;
        int row = h0 - 1 + rp;
        short8 v = {0, 0, 0, 0, 0, 0, 0, 0};
        if ((unsigned)row < 32u)
          v = *(const short8*)&xT[(b * 1024 + row * 32 + w) * 256 + c0 + cg * 8];
        int rowS = rp * 34 + w + 1;
        *(short8*)&Xc[rowS * 72 + ((cg ^ (rowS & 7)) * 8)] = v;
      }
      __syncthreads();
#pragma unroll
      for (int ks = 0; ks < 2; ++ks) {
        int ko = c0 + ks * 32 + g * 8;
        int slot = ks * 4 + g;
#pragma unroll
        for (int r = 0; r < 3; ++r)
#pragma unroll
          for (int s = 0; s < 3; ++s) {
            int tap = r * 3 + s;
            short8 a0 = *(const short8*)&WcT[(tap * 256 + co0 + ln) * 256 + ko];
            short8 a1 =
                *(const short8*)&WcT[(tap * 256 + co0 + 16 + ln) * 256 + ko];
#pragma unroll
            for (int jt = 0; jt < 2; ++jt) {
              int rowp = (nh + r) * 34 + jt * 16 + ln + s;
              short8 bf =
                  *(const short8*)&Xc[rowp * 72 + ((slot ^ (rowp & 7)) * 8)];
              acc[0][jt] = __builtin_amdgcn_mfma_f32_16x16x32_bf16(
                  a0, bf, acc[0][jt], 0, 0, 0);
              acc[1][jt] = __builtin_amdgcn_mfma_f32_16x16x32_bf16(
                  a1, bf, acc[1][jt], 0, 0, 0);
            }
          }
      }
    }

#pragma unroll
    for (int it = 0; it < 2; ++it)
#pragma unroll
      for (int r4 = 0; r4 < 4; ++r4) {
        int co = co0 + it * 16 + g * 4 + r4;
        float bias = cb[co];
#pragma unroll
        for (int jt = 0; jt < 2; ++jt) {
          int w = jt * 16 + ln;
          out[((b * 512 + co) * 32 + h0 + nh) * 32 + w] =
              acc[it][jt][r4] + bias;
        }
      }
    return;
  }

  // ==================== attn: 32x32x16, in-register P ====================
  u16* kvb = (u16*)smem;
  int h = idx >> 3, qt = idx & 7;
  int nw = qt * 128 + wave * 32;
  int lq = lane & 31, hi = lane >> 5;

  const u16* kb = kT + (b * 8 + h) * (1024 * 32);
  const u16* qb = qT + (b * 8 + h) * (1024 * 32);
  const u16* vb = vB + (b * 256 + h * 32) * 1024;

  short8 qf0 = *(const short8*)&qb[(nw + lq) * 32 + hi * 8];
  short8 qf1 = *(const short8*)&qb[(nw + lq) * 32 + 16 + hi * 8];

  int sr = tid >> 2, ss = tid & 3;
  int dvr = tid >> 3, vs = tid & 7;
  const u16* ksrc = kb + sr * 32 + ss * 8;
  const u16* vsrc = vb + dvr * 1024 + vs * 8;
  int kdst = sr * 40 + ss * 8;
  int vdst = 2560 + dvr * 72 + vs * 8;

  int kr0 = lq * 40;
  int kr1 = (32 + lq) * 40;
  int vr = 2560 + lq * 72;

  f32x16 o0 = {};
  float mx = -1e30f, l = 0.f;

  short8 kp = *(const short8*)ksrc;
  short8 vp = *(const short8*)vsrc;
  *(short8*)&kvb[kdst] = kp;
  *(short8*)&kvb[vdst] = vp;
  __syncthreads();
  kp = *(const short8*)(ksrc + 2048);
  vp = *(const short8*)(vsrc + 64);

  for (int mt = 0; mt < 16; ++mt) {
    u16* bc = kvb + (mt & 1) * 4864;
    if (mt < 15) {
      u16* bn = kvb + ((mt + 1) & 1) * 4864;
      *(short8*)&bn[kdst] = kp;
      *(short8*)&bn[vdst] = vp;
    }
    if (mt < 14) {
      kp = *(const short8*)(ksrc + (mt + 2) * 2048);
      vp = *(const short8*)(vsrc + (mt + 2) * 64);
    }

    short8 ka00 = *(const short8*)&bc[kr0 + hi * 8];
    short8 ka01 = *(const short8*)&bc[kr0 + 16 + hi * 8];
    short8 ka10 = *(const short8*)&bc[kr1 + hi * 8];
    short8 ka11 = *(const short8*)&bc[kr1 + 16 + hi * 8];
    f32x16 s0t = {}, s1t = {};
    __builtin_amdgcn_s_setprio(1);
    s0t = __builtin_amdgcn_mfma_f32_32x32x16_bf16(ka00, qf0, s0t, 0, 0, 0);
    s0t = __builtin_amdgcn_mfma_f32_32x32x16_bf16(ka01, qf1, s0t, 0, 0, 0);
    s1t = __builtin_amdgcn_mfma_f32_32x32x16_bf16(ka10, qf0, s1t, 0, 0, 0);
    s1t = __builtin_amdgcn_mfma_f32_32x32x16_bf16(ka11, qf1, s1t, 0, 0, 0);
    __builtin_amdgcn_s_setprio(0);

    short8 vf0 = *(const short8*)&bc[vr + hi * 8];
    short8 vf1 = *(const short8*)&bc[vr + 16 + hi * 8];
    short8 vf2 = *(const short8*)&bc[vr + 32 + hi * 8];
    short8 vf3 = *(const short8*)&bc[vr + 48 + hi * 8];

    float tmax = s0t[0];
#pragma unroll
    for (int r = 1; r < 16; ++r) tmax = fmaxf(tmax, s0t[r]);
#pragma unroll
    for (int r = 0; r < 16; ++r) tmax = fmaxf(tmax, s1t[r]);
    tmax = fmaxf(tmax, __shfl_xor(tmax, 32));

    if (!__all(tmax - mx <= 8.0f)) {
      float nm = fmaxf(mx, tmax);
      float sc = __builtin_amdgcn_exp2f(mx - nm);
#pragma unroll
      for (int r = 0; r < 16; ++r) o0[r] *= sc;
      l *= sc;
      mx = nm;
    }

#pragma unroll
    for (int r = 0; r < 16; ++r) {
      s0t[r] = __builtin_amdgcn_exp2f(s0t[r] - mx);
      s1t[r] = __builtin_amdgcn_exp2f(s1t[r] - mx);
    }
    float ts = 0.f;
#pragma unroll
    for (int r = 0; r < 16; ++r) ts += s0t[r] + s1t[r];
    ts += __shfl_xor(ts, 32);
    l += ts;

    __builtin_amdgcn_s_setprio(1);
#define PV_CHUNK(SV, CB, VF)                                                  \
  {                                                                           \
    unsigned A0 = packP(SV[(CB) + 0], SV[(CB) + 1]);                          \
    unsigned A1 = packP(SV[(CB) + 2], SV[(CB) + 3]);                          \
    unsigned B0 = packP(SV[(CB) + 4], SV[(CB) + 5]);                          \
    unsigned B1 = packP(SV[(CB) + 6], SV[(CB) + 7]);                          \
    unsigned sm0 = hi ? A0 : B0, sm1 = hi ? A1 : B1;                          \
    unsigned r0_ = (unsigned)__shfl_xor((int)sm0, 32);                        \
    unsigned r1_ = (unsigned)__shfl_xor((int)sm1, 32);                        \
    uint4 fw;                                                                 \
    fw.x = hi ? r0_ : A0;                                                     \
    fw.y = hi ? r1_ : A1;                                                     \
    fw.z = hi ? B0 : r0_;                                                     \
    fw.w = hi ? B1 : r1_;                                                     \
    short8 pf = __builtin_bit_cast(short8, fw);                               \
    o0 = __builtin_amdgcn_mfma_f32_32x32x16_bf16(VF, pf, o0, 0, 0, 0);        \
  }
    PV_CHUNK(s0t, 0, vf0)
    PV_CHUNK(s0t, 8, vf1)
    PV_CHUNK(s1t, 0, vf2)
    PV_CHUNK(s1t, 8, vf3)
#undef PV_CHUNK
    __builtin_amdgcn_s_setprio(0);

    __syncthreads();
  }

  float rl = 1.f / l;
  float* ob = out + (b * 512 + 256 + h * 32) * 1024 + nw + lq;
#pragma unroll
  for (int r = 0; r < 16; ++r) {
    int dv = (r & 3) + 8 * (r >> 2) + 4 * hi;
    ob[dv * 1024] = o0[r] * rl;
  }
}

// ---------------------------------------------------------------------------
extern "C" void kernel_launch(void* const* d_in, const int* in_sizes, int n_in,
                              void* d_out, int out_size, void* d_ws,
                              size_t ws_size, hipStream_t stream) {
  const float* x  = (const float*)d_in[0];
  const float* cw = (const float*)d_in[1];
  const float* cb = (const float*)d_in[2];
  const float* aw = (const float*)d_in[3];
  const float* ab = (const float*)d_in[4];
  float* out = (float*)d_out;

  char* ws = (char*)d_ws;
  u16* vB  = (u16*)ws;                           //  4,194,304 B
  u16* kT  = (u16*)(ws + 4194304);               //  4,194,304 B
  u16* qT  = (u16*)(ws + 8388608);               //  4,194,304 B
  u16* xT  = (u16*)(ws + 12582912);              //  4,194,304 B
  u16* WcT = (u16*)(ws + 16777216);              //  1,179,648 B
  u16* WaT = (u16*)(ws + 17956864);              //    393,216 B

  prep_kernel<<<320, 256, 0, stream>>>(x, cw, aw, xT, WcT, WaT);
  kqv_kernel<<<768, 256, 0, stream>>>(xT, WaT, ab, kT, qT, vB);
  conv_attn_kernel<<<1024, 256, 0, stream>>>(xT, WcT, cb, kT, qT, vB, out);
}

// Round 11
// 54.581 us; speedup vs baseline: 1.7101x; 1.7101x over previous
//
#include <hip/hip_runtime.h>

// AAConv: 3x3 conv (256->256) + 1x1 conv (256->768 kqv) + 8-head attention
// (HW=1024, DKH=DVH=32), out = concat([conv_out, attn_out]) (8,512,32,32) fp32.
//
// R15: REVERT R14 (conv quarter-split doubled staging:compute ratio ->
//   76us fused; occupancy metric reflects drain imbalance, not residency).
//   Back to R13 structure (grid 768, conv 2h x 128co rem==2 decode), plus
//   ONE change: attn PV accumulator split o0 -> o0a/o0b (serial MFMA chain
//   4 -> 2 per iter; summed in epilogue; +16 VGPR, no occupancy effect).
//
// ws layout (bytes): vB @0 (4,194,304) | kT @4,194,304 (4,194,304)
//   | qT @8,388,608 (4,194,304) | xT @12,582,912 (4,194,304)
//   | WcT @16,777,216 (1,179,648) | WaT @17,956,864 (393,216)

typedef __attribute__((ext_vector_type(8))) short short8;
typedef __attribute__((ext_vector_type(4))) float f32x4;
typedef __attribute__((ext_vector_type(16))) float f32x16;
typedef unsigned short u16;

// 1/sqrt(32) * log2(e): Q pre-scale folding softmax into exp2 domain.
#define QSCALE 0.25503487629898483f

__device__ inline u16 f2bf(float f) {
  unsigned u = __builtin_bit_cast(unsigned, f);
  return (u16)((u + 0x7FFFu + ((u >> 16) & 1u)) >> 16);
}
__device__ inline unsigned pack2bf(float a, float b) {
  return (unsigned)f2bf(a) | ((unsigned)f2bf(b) << 16);
}
// pack two f32 -> two bf16 (round-half-up) in one perm.
__device__ inline unsigned packP(float a, float b) {
  unsigned au = __builtin_bit_cast(unsigned, a) + 0x8000u;
  unsigned bu = __builtin_bit_cast(unsigned, b) + 0x8000u;
  return __builtin_amdgcn_perm(bu, au, 0x07060302u);
}

// ---------------------------------------------------------------------------
// prep: grid 320. xT path uses packP (pairwise) for the bf16 convert.
// ---------------------------------------------------------------------------
__global__ __launch_bounds__(256) void prep_kernel(const float* __restrict__ x,
                                                   const float* __restrict__ cw,
                                                   const float* __restrict__ aw,
                                                   u16* __restrict__ xT,
                                                   u16* __restrict__ WcT,
                                                   u16* __restrict__ WaT) {
  __shared__ float T[64][65];
  int bid = blockIdx.x, tid = threadIdx.x;

  if (bid < 128) {
    int b = bid >> 4, n0 = (bid & 15) * 64;
#pragma unroll
    for (int rep = 0; rep < 2; ++rep) {
      int flat = rep * 256 + tid;          // 0..511
      int n = flat & 63, cg = flat >> 6;   // cg 0..7 -> 32 ci each
      const float* xs = x + b * 256 * 1024 + n0 + n;
#pragma unroll
      for (int q = 0; q < 4; ++q) {
        uint4 pk;
#pragma unroll
        for (int jj = 0; jj < 4; ++jj) {
          float a = xs[(cg * 32 + q * 8 + 2 * jj) * 1024];
          float c = xs[(cg * 32 + q * 8 + 2 * jj + 1) * 1024];
          ((unsigned*)&pk)[jj] = packP(a, c);
        }
        *(uint4*)&xT[(b * 1024 + n0 + n) * 256 + cg * 32 + q * 8] = pk;
      }
    }
    return;
  }

  int tt = bid - 128;
  int chunk = tt >> 4, t = tt & 15;
  int ci0 = (t & 3) * 64, r0 = (t >> 2) * 64;
  bool isconv = chunk < 9;
  float scale = (chunk == 10) ? QSCALE : 1.0f;

#pragma unroll
  for (int rep = 0; rep < 16; ++rep) {
    int flat = rep * 256 + tid;
    int i = flat >> 6, j = flat & 63;     // i = ci-local, j = dst-row-local
    T[i][j] = isconv ? cw[(chunk * 256 + ci0 + i) * 256 + r0 + j]
                     : aw[(ci0 + i) * 768 + (chunk - 9) * 256 + r0 + j];
  }
  __syncthreads();
#pragma unroll
  for (int rep = 0; rep < 4; ++rep) {
    int flat = rep * 256 + tid;
    int jj = flat >> 4, qq = flat & 15;   // dst row r0+jj, ci ci0+qq*4
    float v0 = T[qq * 4 + 0][jj] * scale;
    float v1 = T[qq * 4 + 1][jj] * scale;
    float v2 = T[qq * 4 + 2][jj] * scale;
    float v3 = T[qq * 4 + 3][jj] * scale;
    uint2 pk = {pack2bf(v0, v1), pack2bf(v2, v3)};
    if (isconv)
      *(uint2*)&WcT[(chunk * 256 + r0 + jj) * 256 + ci0 + qq * 4] = pk;
    else
      *(uint2*)&WaT[((chunk - 9) * 256 + r0 + jj) * 256 + ci0 + qq * 4] = pk;
  }
}

// ---------------------------------------------------------------------------
// kqv: GEMM [768x256]x[256x1024] per batch. grid 768. b = bid&7 (XCD-local).
// R12: LDS-staged K-step tiles, double-buffered, 2-step register prefetch.
// ---------------------------------------------------------------------------
__global__ __launch_bounds__(256) void kqv_kernel(const u16* __restrict__ xT,
                                                  const u16* __restrict__ WaT,
                                                  const float* __restrict__ ab,
                                                  u16* __restrict__ kT,
                                                  u16* __restrict__ qT,
                                                  u16* __restrict__ vB) {
  __shared__ __align__(16) u16 S[15360];      // 30 KB: 2 x (A 5120 + B 2560)
  int bid = blockIdx.x;
  int b = bid & 7, idx = bid >> 3;       // XCD-local batch
  int ot = idx >> 4, nt = idx & 15;      // idx 0..95 -> ot 0..5, nt 0..15
  int tid = threadIdx.x, wave = tid >> 6, lane = tid & 63;
  int ln = lane & 15, g = lane >> 4;
  int o0 = ot * 128 + (wave & 1) * 64;
  int n0 = nt * 64 + (wave >> 1) * 32;
  const u16* xb = xT + b * 1024 * 256;

  // staging coords: row rA (0..63 for B, rA and rA+64 for A), 16B slot slA
  int rA = tid >> 2, slA = tid & 3;
  const u16* aS0 = WaT + (ot * 128 + rA) * 256 + slA * 8;
  const u16* aS1 = aS0 + 64 * 256;
  const u16* bS = xb + (nt * 64 + rA) * 256 + slA * 8;
  int aD0 = rA * 40 + slA * 8;
  int aD1 = aD0 + 64 * 40;
  int bD = 5120 + rA * 40 + slA * 8;

  // per-wave fragment LDS offsets
  int aF = ((wave & 1) * 64 + ln) * 40 + g * 8;
  int bF = 5120 + ((wave >> 1) * 32 + ln) * 40 + g * 8;

  f32x4 acc[4][2];
#pragma unroll
  for (int i = 0; i < 4; ++i)
#pragma unroll
    for (int j = 0; j < 2; ++j) acc[i][j] = (f32x4){0.f, 0.f, 0.f, 0.f};

  // prologue: stage step 0 into buf0; prefetch step 1 into regs
  *(short8*)&S[aD0] = *(const short8*)aS0;
  *(short8*)&S[aD1] = *(const short8*)aS1;
  *(short8*)&S[bD] = *(const short8*)bS;
  __syncthreads();
  short8 pa0 = *(const short8*)(aS0 + 32);
  short8 pa1 = *(const short8*)(aS1 + 32);
  short8 pb = *(const short8*)(bS + 32);

#pragma unroll
  for (int s = 0; s < 8; ++s) {
    const u16* buf = S + (s & 1) * 7680;
    short8 a0 = *(const short8*)&buf[aF];
    short8 a1 = *(const short8*)&buf[aF + 16 * 40];
    short8 a2 = *(const short8*)&buf[aF + 32 * 40];
    short8 a3 = *(const short8*)&buf[aF + 48 * 40];
    short8 b0 = *(const short8*)&buf[bF];
    short8 b1 = *(const short8*)&buf[bF + 16 * 40];
    acc[0][0] = __builtin_amdgcn_mfma_f32_16x16x32_bf16(a0, b0, acc[0][0], 0, 0, 0);
    acc[0][1] = __builtin_amdgcn_mfma_f32_16x16x32_bf16(a0, b1, acc[0][1], 0, 0, 0);
    acc[1][0] = __builtin_amdgcn_mfma_f32_16x16x32_bf16(a1, b0, acc[1][0], 0, 0, 0);
    acc[1][1] = __builtin_amdgcn_mfma_f32_16x16x32_bf16(a1, b1, acc[1][1], 0, 0, 0);
    acc[2][0] = __builtin_amdgcn_mfma_f32_16x16x32_bf16(a2, b0, acc[2][0], 0, 0, 0);
    acc[2][1] = __builtin_amdgcn_mfma_f32_16x16x32_bf16(a2, b1, acc[2][1], 0, 0, 0);
    acc[3][0] = __builtin_amdgcn_mfma_f32_16x16x32_bf16(a3, b0, acc[3][0], 0, 0, 0);
    acc[3][1] = __builtin_amdgcn_mfma_f32_16x16x32_bf16(a3, b1, acc[3][1], 0, 0, 0);
    if (s < 7) {
      u16* nb = S + ((s + 1) & 1) * 7680;
      *(short8*)&nb[aD0] = pa0;
      *(short8*)&nb[aD1] = pa1;
      *(short8*)&nb[bD] = pb;
      if (s < 6) {
        pa0 = *(const short8*)(aS0 + (s + 2) * 32);
        pa1 = *(const short8*)(aS1 + (s + 2) * 32);
        pb = *(const short8*)(bS + (s + 2) * 32);
      }
    }
    __syncthreads();
  }

  if (ot >= 4) {
    // V: natural [dv][m] layout, scalar bf16 stores.
#pragma unroll
    for (int it = 0; it < 4; ++it)
#pragma unroll
      for (int r = 0; r < 4; ++r) {
        int o = o0 + it * 16 + g * 4 + r;
        float bias = ab[o];
#pragma unroll
        for (int jt = 0; jt < 2; ++jt) {
          int n = n0 + jt * 16 + ln;
          vB[(b * 256 + (o - 512)) * 1024 + n] = f2bf(acc[it][jt][r] + bias);
        }
      }
    return;
  }

  // K/Q: transpose 128o x 64n tile via LDS (aliases S), write [b][h][n][d].
  u16* Tt = S;                              // [64][136]
  bool isQ = (ot >= 2);
  float bs = isQ ? QSCALE : 1.0f;
  int olb = (wave & 1) * 64;
  int nlb = (wave >> 1) * 32;
#pragma unroll
  for (int it = 0; it < 4; ++it)
#pragma unroll
    for (int jt = 0; jt < 2; ++jt) {
      int ol = olb + it * 16 + g * 4;
      int nl = nlb + jt * 16 + ln;
      int og = ot * 128 + ol;
      float v0 = acc[it][jt][0] + ab[og + 0] * bs;
      float v1 = acc[it][jt][1] + ab[og + 1] * bs;
      float v2 = acc[it][jt][2] + ab[og + 2] * bs;
      float v3 = acc[it][jt][3] + ab[og + 3] * bs;
      uint2 pk = {pack2bf(v0, v1), pack2bf(v2, v3)};
      *(uint2*)&Tt[nl * 136 + ol] = pk;
    }
  __syncthreads();
  u16* dst = isQ ? qT : kT;
#pragma unroll
  for (int rep = 0; rep < 4; ++rep) {
    int flat = rep * 256 + tid;
    int o8 = flat & 15, nl = flat >> 4;
    short8 v = *(const short8*)&Tt[nl * 136 + o8 * 8];
    int og256 = (ot & 1) * 128 + o8 * 8;   // o within the 256-row K (or Q) range
    int hh = og256 >> 5, d0 = og256 & 31;
    int ng = nt * 64 + nl;
    *(short8*)&dst[((b * 8 + hh) * 1024 + ng) * 32 + d0] = v;
  }
}

// ---------------------------------------------------------------------------
// FUSED conv + attn. grid 768. xcd = bid&7 -> batch b; sub = bid>>3 (0..95);
// rem = sub%3: rem==2 -> conv idx=sub/3 (0..31), else attn idx=(sub/3)*2+rem.
//   conv (R10): hp = idx>>1 (2 h-rows), coh = idx&1; Xc slot^=row&7.
//   attn (R11 + split PV acc): h = idx>>3, qt = idx&7; 4 waves x 32 q-cols.
// LDS union: conv Xc 4*34*72 u16 = 19.6KB; attn kv[2][4864] u16 = 19.0KB.
// ---------------------------------------------------------------------------
__global__ __launch_bounds__(256, 3) void conv_attn_kernel(
    const u16* __restrict__ xT, const u16* __restrict__ WcT,
    const float* __restrict__ cb, const u16* __restrict__ kT,
    const u16* __restrict__ qT, const u16* __restrict__ vB,
    float* __restrict__ out) {
  __shared__ __align__(16) unsigned char smem[19584];

  int bid = blockIdx.x;
  int b = bid & 7;                  // XCD-local batch
  int sub = bid >> 3;               // 0..95
  int trip = sub / 3;
  int rem = sub - trip * 3;
  int tid = threadIdx.x;
  int wave = tid >> 6, lane = tid & 63;

  if (rem == 2) {
    // ========== conv: R10 body (Xc 16B-slot swizzled by row) ==========
    int ln = lane & 15, g = lane >> 4;
    u16* Xc = (u16*)smem;           // [4*34 rows][72], 19.6 KB
    int hp = trip >> 1, coh = trip & 1;
    int h0 = hp * 2;
    int co0 = coh * 128 + wave * 32;

    f32x4 acc[2][4];
#pragma unroll
    for (int i = 0; i < 2; ++i)
#pragma unroll
      for (int j = 0; j < 4; ++j) acc[i][j] = (f32x4){0.f, 0.f, 0.f, 0.f};

    {
      int rp = tid >> 6, rest = tid & 63;
      int which = rest >> 5, cp = rest & 31;
      *(unsigned*)&Xc[(rp * 34 + which * 33) * 72 + cp * 2] = 0u;
    }

    for (int c0 = 0; c0 < 256; c0 += 64) {
      __syncthreads();
#pragma unroll
      for (int rep = 0; rep < 4; ++rep) {
        int flat = rep * 256 + tid;
        int cg = flat & 7, w = (flat >> 3) & 31, rp = flat >> 8;
        int row = h0 - 1 + rp;
        short8 v = {0, 0, 0, 0, 0, 0, 0, 0};
        if ((unsigned)row < 32u)
          v = *(const short8*)&xT[(b * 1024 + row * 32 + w) * 256 + c0 + cg * 8];
        int rowS = rp * 34 + w + 1;
        *(short8*)&Xc[rowS * 72 + ((cg ^ (rowS & 7)) * 8)] = v;
      }
      __syncthreads();
#pragma unroll
      for (int ks = 0; ks < 2; ++ks) {
        int ko = c0 + ks * 32 + g * 8;
        int slot = ks * 4 + g;
#pragma unroll
        for (int r = 0; r < 3; ++r)
#pragma unroll
          for (int s = 0; s < 3; ++s) {
            int tap = r * 3 + s;
            short8 a0 = *(const short8*)&WcT[(tap * 256 + co0 + ln) * 256 + ko];
            short8 a1 =
                *(const short8*)&WcT[(tap * 256 + co0 + 16 + ln) * 256 + ko];
#pragma unroll
            for (int jt = 0; jt < 4; ++jt) {
              int rowp = ((jt >> 1) + r) * 34 + (jt & 1) * 16 + ln + s;
              short8 bf =
                  *(const short8*)&Xc[rowp * 72 + ((slot ^ (rowp & 7)) * 8)];
              acc[0][jt] = __builtin_amdgcn_mfma_f32_16x16x32_bf16(
                  a0, bf, acc[0][jt], 0, 0, 0);
              acc[1][jt] = __builtin_amdgcn_mfma_f32_16x16x32_bf16(
                  a1, bf, acc[1][jt], 0, 0, 0);
            }
          }
      }
    }

#pragma unroll
    for (int it = 0; it < 2; ++it)
#pragma unroll
      for (int r4 = 0; r4 < 4; ++r4) {
        int co = co0 + it * 16 + g * 4 + r4;
        float bias = cb[co];
#pragma unroll
        for (int jt = 0; jt < 4; ++jt) {
          int h = h0 + (jt >> 1), w = (jt & 1) * 16 + ln;
          out[((b * 512 + co) * 32 + h) * 32 + w] = acc[it][jt][r4] + bias;
        }
      }
    return;
  }

  // ========== attn: 32x32x16, in-register P, split PV accumulators ==========
  u16* kvb = (u16*)smem;
  int idx = trip * 2 + rem;               // 0..63
  int h = idx >> 3, qt = idx & 7;
  int nw = qt * 128 + wave * 32;
  int lq = lane & 31, hi = lane >> 5;

  const u16* kb = kT + (b * 8 + h) * (1024 * 32);
  const u16* qb = qT + (b * 8 + h) * (1024 * 32);
  const u16* vb = vB + (b * 256 + h * 32) * 1024;

  short8 qf0 = *(const short8*)&qb[(nw + lq) * 32 + hi * 8];
  short8 qf1 = *(const short8*)&qb[(nw + lq) * 32 + 16 + hi * 8];

  int sr = tid >> 2, ss = tid & 3;
  int dvr = tid >> 3, vs = tid & 7;
  const u16* ksrc = kb + sr * 32 + ss * 8;
  const u16* vsrc = vb + dvr * 1024 + vs * 8;
  int kdst = sr * 40 + ss * 8;
  int vdst = 2560 + dvr * 72 + vs * 8;

  int kr0 = lq * 40;
  int kr1 = (32 + lq) * 40;
  int vr = 2560 + lq * 72;

  f32x16 o0a = {}, o0b = {};
  float mx = -1e30f, l = 0.f;

  short8 kp = *(const short8*)ksrc;
  short8 vp = *(const short8*)vsrc;
  *(short8*)&kvb[kdst] = kp;
  *(short8*)&kvb[vdst] = vp;
  __syncthreads();
  kp = *(const short8*)(ksrc + 2048);
  vp = *(const short8*)(vsrc + 64);

  for (int mt = 0; mt < 16; ++mt) {
    u16* bc = kvb + (mt & 1) * 4864;
    if (mt < 15) {
      u16* bn = kvb + ((mt + 1) & 1) * 4864;
      *(short8*)&bn[kdst] = kp;
      *(short8*)&bn[vdst] = vp;
    }
    if (mt < 14) {
      kp = *(const short8*)(ksrc + (mt + 2) * 2048);
      vp = *(const short8*)(vsrc + (mt + 2) * 64);
    }

    short8 ka00 = *(const short8*)&bc[kr0 + hi * 8];
    short8 ka01 = *(const short8*)&bc[kr0 + 16 + hi * 8];
    short8 ka10 = *(const short8*)&bc[kr1 + hi * 8];
    short8 ka11 = *(const short8*)&bc[kr1 + 16 + hi * 8];
    f32x16 s0t = {}, s1t = {};
    __builtin_amdgcn_s_setprio(1);
    s0t = __builtin_amdgcn_mfma_f32_32x32x16_bf16(ka00, qf0, s0t, 0, 0, 0);
    s1t = __builtin_amdgcn_mfma_f32_32x32x16_bf16(ka10, qf0, s1t, 0, 0, 0);
    s0t = __builtin_amdgcn_mfma_f32_32x32x16_bf16(ka01, qf1, s0t, 0, 0, 0);
    s1t = __builtin_amdgcn_mfma_f32_32x32x16_bf16(ka11, qf1, s1t, 0, 0, 0);
    __builtin_amdgcn_s_setprio(0);

    short8 vf0 = *(const short8*)&bc[vr + hi * 8];
    short8 vf1 = *(const short8*)&bc[vr + 16 + hi * 8];
    short8 vf2 = *(const short8*)&bc[vr + 32 + hi * 8];
    short8 vf3 = *(const short8*)&bc[vr + 48 + hi * 8];

    float tmax = s0t[0];
#pragma unroll
    for (int r = 1; r < 16; ++r) tmax = fmaxf(tmax, s0t[r]);
#pragma unroll
    for (int r = 0; r < 16; ++r) tmax = fmaxf(tmax, s1t[r]);
    tmax = fmaxf(tmax, __shfl_xor(tmax, 32));

    if (!__all(tmax - mx <= 8.0f)) {
      float nm = fmaxf(mx, tmax);
      float sc = __builtin_amdgcn_exp2f(mx - nm);
#pragma unroll
      for (int r = 0; r < 16; ++r) {
        o0a[r] *= sc;
        o0b[r] *= sc;
      }
      l *= sc;
      mx = nm;
    }

#pragma unroll
    for (int r = 0; r < 16; ++r) {
      s0t[r] = __builtin_amdgcn_exp2f(s0t[r] - mx);
      s1t[r] = __builtin_amdgcn_exp2f(s1t[r] - mx);
    }
    float ts = 0.f;
#pragma unroll
    for (int r = 0; r < 16; ++r) ts += s0t[r] + s1t[r];
    ts += __shfl_xor(ts, 32);
    l += ts;

    __builtin_amdgcn_s_setprio(1);
#define PV_CHUNK(SV, CB, VF, ACC)                                             \
  {                                                                           \
    unsigned A0 = packP(SV[(CB) + 0], SV[(CB) + 1]);                          \
    unsigned A1 = packP(SV[(CB) + 2], SV[(CB) + 3]);                          \
    unsigned B0 = packP(SV[(CB) + 4], SV[(CB) + 5]);                          \
    unsigned B1 = packP(SV[(CB) + 6], SV[(CB) + 7]);                          \
    unsigned sm0 = hi ? A0 : B0, sm1 = hi ? A1 : B1;                          \
    unsigned r0_ = (unsigned)__shfl_xor((int)sm0, 32);                        \
    unsigned r1_ = (unsigned)__shfl_xor((int)sm1, 32);                        \
    uint4 fw;                                                                 \
    fw.x = hi ? r0_ : A0;                                                     \
    fw.y = hi ? r1_ : A1;                                                     \
    fw.z = hi ? B0 : r0_;                                                     \
    fw.w = hi ? B1 : r1_;                                                     \
    short8 pf = __builtin_bit_cast(short8, fw);                               \
    ACC = __builtin_amdgcn_mfma_f32_32x32x16_bf16(VF, pf, ACC, 0, 0, 0);      \
  }
    PV_CHUNK(s0t, 0, vf0, o0a)
    PV_CHUNK(s0t, 8, vf1, o0b)
    PV_CHUNK(s1t, 0, vf2, o0a)
    PV_CHUNK(s1t, 8, vf3, o0b)
#undef PV_CHUNK
    __builtin_amdgcn_s_setprio(0);

    __syncthreads();
  }

  float rl = 1.f / l;
  float* ob = out + (b * 512 + 256 + h * 32) * 1024 + nw + lq;
#pragma unroll
  for (int r = 0; r < 16; ++r) {
    int dv = (r & 3) + 8 * (r >> 2) + 4 * hi;
    ob[dv * 1024] = (o0a[r] + o0b[r]) * rl;
  }
}

// ---------------------------------------------------------------------------
extern "C" void kernel_launch(void* const* d_in, const int* in_sizes, int n_in,
                              void* d_out, int out_size, void* d_ws,
                              size_t ws_size, hipStream_t stream) {
  const float* x  = (const float*)d_in[0];
  const float* cw = (const float*)d_in[1];
  const float* cb = (const float*)d_in[2];
  const float* aw = (const float*)d_in[3];
  const float* ab = (const float*)d_in[4];
  float* out = (float*)d_out;

  char* ws = (char*)d_ws;
  u16* vB  = (u16*)ws;                           //  4,194,304 B
  u16* kT  = (u16*)(ws + 4194304);               //  4,194,304 B
  u16* qT  = (u16*)(ws + 8388608);               //  4,194,304 B
  u16* xT  = (u16*)(ws + 12582912);              //  4,194,304 B
  u16* WcT = (u16*)(ws + 16777216);              //  1,179,648 B
  u16* WaT = (u16*)(ws + 17956864);              //    393,216 B

  prep_kernel<<<320, 256, 0, stream>>>(x, cw, aw, xT, WcT, WaT);
  kqv_kernel<<<768, 256, 0, stream>>>(xT, WaT, ab, kT, qT, vB);
  conv_attn_kernel<<<768, 256, 0, stream>>>(xT, WcT, cb, kT, qT, vB, out);
}

// Round 12
// 54.330 us; speedup vs baseline: 1.7180x; 1.0046x over previous
//
#include <hip/hip_runtime.h>

// AAConv: 3x3 conv (256->256) + 1x1 conv (256->768 kqv) + 8-head attention
// (HW=1024, DKH=DVH=32), out = concat([conv_out, attn_out]) (8,512,32,32) fp32.
//
// R16: attn cross-iter pipeline (T15). R15's plateau = serial per-iter chain
//   (QK -> SM -> PV, ~2000cy). Now QK^T(t+1) is issued BEFORE softmax(t)+PV(t)
//   so its LDS-read+MFMA latency hides under SM's VALU burst (separate pipes).
//   4 rotated LDS buffers (static indices via unroll 4), one barrier/iter;
//   buffer lifetimes distinct mod 4. S-state doubled (sc+sn).
// conv/kqv/prep identical to R15.
//
// ws layout (bytes): vB @0 (4,194,304) | kT @4,194,304 (4,194,304)
//   | qT @8,388,608 (4,194,304) | xT @12,582,912 (4,194,304)
//   | WcT @16,777,216 (1,179,648) | WaT @17,956,864 (393,216)

typedef __attribute__((ext_vector_type(8))) short short8;
typedef __attribute__((ext_vector_type(4))) float f32x4;
typedef __attribute__((ext_vector_type(16))) float f32x16;
typedef unsigned short u16;

// 1/sqrt(32) * log2(e): Q pre-scale folding softmax into exp2 domain.
#define QSCALE 0.25503487629898483f

__device__ inline u16 f2bf(float f) {
  unsigned u = __builtin_bit_cast(unsigned, f);
  return (u16)((u + 0x7FFFu + ((u >> 16) & 1u)) >> 16);
}
__device__ inline unsigned pack2bf(float a, float b) {
  return (unsigned)f2bf(a) | ((unsigned)f2bf(b) << 16);
}
// pack two f32 -> two bf16 (round-half-up) in one perm.
__device__ inline unsigned packP(float a, float b) {
  unsigned au = __builtin_bit_cast(unsigned, a) + 0x8000u;
  unsigned bu = __builtin_bit_cast(unsigned, b) + 0x8000u;
  return __builtin_amdgcn_perm(bu, au, 0x07060302u);
}

// ---------------------------------------------------------------------------
// prep: grid 320. xT path uses packP (pairwise) for the bf16 convert.
// ---------------------------------------------------------------------------
__global__ __launch_bounds__(256) void prep_kernel(const float* __restrict__ x,
                                                   const float* __restrict__ cw,
                                                   const float* __restrict__ aw,
                                                   u16* __restrict__ xT,
                                                   u16* __restrict__ WcT,
                                                   u16* __restrict__ WaT) {
  __shared__ float T[64][65];
  int bid = blockIdx.x, tid = threadIdx.x;

  if (bid < 128) {
    int b = bid >> 4, n0 = (bid & 15) * 64;
#pragma unroll
    for (int rep = 0; rep < 2; ++rep) {
      int flat = rep * 256 + tid;          // 0..511
      int n = flat & 63, cg = flat >> 6;   // cg 0..7 -> 32 ci each
      const float* xs = x + b * 256 * 1024 + n0 + n;
#pragma unroll
      for (int q = 0; q < 4; ++q) {
        uint4 pk;
#pragma unroll
        for (int jj = 0; jj < 4; ++jj) {
          float a = xs[(cg * 32 + q * 8 + 2 * jj) * 1024];
          float c = xs[(cg * 32 + q * 8 + 2 * jj + 1) * 1024];
          ((unsigned*)&pk)[jj] = packP(a, c);
        }
        *(uint4*)&xT[(b * 1024 + n0 + n) * 256 + cg * 32 + q * 8] = pk;
      }
    }
    return;
  }

  int tt = bid - 128;
  int chunk = tt >> 4, t = tt & 15;
  int ci0 = (t & 3) * 64, r0 = (t >> 2) * 64;
  bool isconv = chunk < 9;
  float scale = (chunk == 10) ? QSCALE : 1.0f;

#pragma unroll
  for (int rep = 0; rep < 16; ++rep) {
    int flat = rep * 256 + tid;
    int i = flat >> 6, j = flat & 63;     // i = ci-local, j = dst-row-local
    T[i][j] = isconv ? cw[(chunk * 256 + ci0 + i) * 256 + r0 + j]
                     : aw[(ci0 + i) * 768 + (chunk - 9) * 256 + r0 + j];
  }
  __syncthreads();
#pragma unroll
  for (int rep = 0; rep < 4; ++rep) {
    int flat = rep * 256 + tid;
    int jj = flat >> 4, qq = flat & 15;   // dst row r0+jj, ci ci0+qq*4
    float v0 = T[qq * 4 + 0][jj] * scale;
    float v1 = T[qq * 4 + 1][jj] * scale;
    float v2 = T[qq * 4 + 2][jj] * scale;
    float v3 = T[qq * 4 + 3][jj] * scale;
    uint2 pk = {pack2bf(v0, v1), pack2bf(v2, v3)};
    if (isconv)
      *(uint2*)&WcT[(chunk * 256 + r0 + jj) * 256 + ci0 + qq * 4] = pk;
    else
      *(uint2*)&WaT[((chunk - 9) * 256 + r0 + jj) * 256 + ci0 + qq * 4] = pk;
  }
}

// ---------------------------------------------------------------------------
// kqv: GEMM [768x256]x[256x1024] per batch. grid 768. b = bid&7 (XCD-local).
// R12: LDS-staged K-step tiles, double-buffered, 2-step register prefetch.
// ---------------------------------------------------------------------------
__global__ __launch_bounds__(256) void kqv_kernel(const u16* __restrict__ xT,
                                                  const u16* __restrict__ WaT,
                                                  const float* __restrict__ ab,
                                                  u16* __restrict__ kT,
                                                  u16* __restrict__ qT,
                                                  u16* __restrict__ vB) {
  __shared__ __align__(16) u16 S[15360];      // 30 KB: 2 x (A 5120 + B 2560)
  int bid = blockIdx.x;
  int b = bid & 7, idx = bid >> 3;       // XCD-local batch
  int ot = idx >> 4, nt = idx & 15;      // idx 0..95 -> ot 0..5, nt 0..15
  int tid = threadIdx.x, wave = tid >> 6, lane = tid & 63;
  int ln = lane & 15, g = lane >> 4;
  int o0 = ot * 128 + (wave & 1) * 64;
  int n0 = nt * 64 + (wave >> 1) * 32;
  const u16* xb = xT + b * 1024 * 256;

  // staging coords: row rA (0..63 for B, rA and rA+64 for A), 16B slot slA
  int rA = tid >> 2, slA = tid & 3;
  const u16* aS0 = WaT + (ot * 128 + rA) * 256 + slA * 8;
  const u16* aS1 = aS0 + 64 * 256;
  const u16* bS = xb + (nt * 64 + rA) * 256 + slA * 8;
  int aD0 = rA * 40 + slA * 8;
  int aD1 = aD0 + 64 * 40;
  int bD = 5120 + rA * 40 + slA * 8;

  // per-wave fragment LDS offsets
  int aF = ((wave & 1) * 64 + ln) * 40 + g * 8;
  int bF = 5120 + ((wave >> 1) * 32 + ln) * 40 + g * 8;

  f32x4 acc[4][2];
#pragma unroll
  for (int i = 0; i < 4; ++i)
#pragma unroll
    for (int j = 0; j < 2; ++j) acc[i][j] = (f32x4){0.f, 0.f, 0.f, 0.f};

  // prologue: stage step 0 into buf0; prefetch step 1 into regs
  *(short8*)&S[aD0] = *(const short8*)aS0;
  *(short8*)&S[aD1] = *(const short8*)aS1;
  *(short8*)&S[bD] = *(const short8*)bS;
  __syncthreads();
  short8 pa0 = *(const short8*)(aS0 + 32);
  short8 pa1 = *(const short8*)(aS1 + 32);
  short8 pb = *(const short8*)(bS + 32);

#pragma unroll
  for (int s = 0; s < 8; ++s) {
    const u16* buf = S + (s & 1) * 7680;
    short8 a0 = *(const short8*)&buf[aF];
    short8 a1 = *(const short8*)&buf[aF + 16 * 40];
    short8 a2 = *(const short8*)&buf[aF + 32 * 40];
    short8 a3 = *(const short8*)&buf[aF + 48 * 40];
    short8 b0 = *(const short8*)&buf[bF];
    short8 b1 = *(const short8*)&buf[bF + 16 * 40];
    acc[0][0] = __builtin_amdgcn_mfma_f32_16x16x32_bf16(a0, b0, acc[0][0], 0, 0, 0);
    acc[0][1] = __builtin_amdgcn_mfma_f32_16x16x32_bf16(a0, b1, acc[0][1], 0, 0, 0);
    acc[1][0] = __builtin_amdgcn_mfma_f32_16x16x32_bf16(a1, b0, acc[1][0], 0, 0, 0);
    acc[1][1] = __builtin_amdgcn_mfma_f32_16x16x32_bf16(a1, b1, acc[1][1], 0, 0, 0);
    acc[2][0] = __builtin_amdgcn_mfma_f32_16x16x32_bf16(a2, b0, acc[2][0], 0, 0, 0);
    acc[2][1] = __builtin_amdgcn_mfma_f32_16x16x32_bf16(a2, b1, acc[2][1], 0, 0, 0);
    acc[3][0] = __builtin_amdgcn_mfma_f32_16x16x32_bf16(a3, b0, acc[3][0], 0, 0, 0);
    acc[3][1] = __builtin_amdgcn_mfma_f32_16x16x32_bf16(a3, b1, acc[3][1], 0, 0, 0);
    if (s < 7) {
      u16* nb = S + ((s + 1) & 1) * 7680;
      *(short8*)&nb[aD0] = pa0;
      *(short8*)&nb[aD1] = pa1;
      *(short8*)&nb[bD] = pb;
      if (s < 6) {
        pa0 = *(const short8*)(aS0 + (s + 2) * 32);
        pa1 = *(const short8*)(aS1 + (s + 2) * 32);
        pb = *(const short8*)(bS + (s + 2) * 32);
      }
    }
    __syncthreads();
  }

  if (ot >= 4) {
    // V: natural [dv][m] layout, scalar bf16 stores.
#pragma unroll
    for (int it = 0; it < 4; ++it)
#pragma unroll
      for (int r = 0; r < 4; ++r) {
        int o = o0 + it * 16 + g * 4 + r;
        float bias = ab[o];
#pragma unroll
        for (int jt = 0; jt < 2; ++jt) {
          int n = n0 + jt * 16 + ln;
          vB[(b * 256 + (o - 512)) * 1024 + n] = f2bf(acc[it][jt][r] + bias);
        }
      }
    return;
  }

  // K/Q: transpose 128o x 64n tile via LDS (aliases S), write [b][h][n][d].
  u16* Tt = S;                              // [64][136]
  bool isQ = (ot >= 2);
  float bs = isQ ? QSCALE : 1.0f;
  int olb = (wave & 1) * 64;
  int nlb = (wave >> 1) * 32;
#pragma unroll
  for (int it = 0; it < 4; ++it)
#pragma unroll
    for (int jt = 0; jt < 2; ++jt) {
      int ol = olb + it * 16 + g * 4;
      int nl = nlb + jt * 16 + ln;
      int og = ot * 128 + ol;
      float v0 = acc[it][jt][0] + ab[og + 0] * bs;
      float v1 = acc[it][jt][1] + ab[og + 1] * bs;
      float v2 = acc[it][jt][2] + ab[og + 2] * bs;
      float v3 = acc[it][jt][3] + ab[og + 3] * bs;
      uint2 pk = {pack2bf(v0, v1), pack2bf(v2, v3)};
      *(uint2*)&Tt[nl * 136 + ol] = pk;
    }
  __syncthreads();
  u16* dst = isQ ? qT : kT;
#pragma unroll
  for (int rep = 0; rep < 4; ++rep) {
    int flat = rep * 256 + tid;
    int o8 = flat & 15, nl = flat >> 4;
    short8 v = *(const short8*)&Tt[nl * 136 + o8 * 8];
    int og256 = (ot & 1) * 128 + o8 * 8;   // o within the 256-row K (or Q) range
    int hh = og256 >> 5, d0 = og256 & 31;
    int ng = nt * 64 + nl;
    *(short8*)&dst[((b * 8 + hh) * 1024 + ng) * 32 + d0] = v;
  }
}

// ---------------------------------------------------------------------------
// FUSED conv + attn. grid 768. xcd = bid&7 -> batch b; sub = bid>>3 (0..95);
// rem = sub%3: rem==2 -> conv idx=sub/3 (0..31), else attn idx=(sub/3)*2+rem.
//   conv (R10): hp = idx>>1 (2 h-rows), coh = idx&1; Xc slot^=row&7.
//   attn (R16): 32x32x16 swapped QK, cross-iter pipeline, 4 LDS buffers.
// LDS union: conv Xc 19.6KB; attn 4 x 4864 u16 = 38.9KB -> smem 38912B.
// ---------------------------------------------------------------------------
__global__ __launch_bounds__(256, 3) void conv_attn_kernel(
    const u16* __restrict__ xT, const u16* __restrict__ WcT,
    const float* __restrict__ cb, const u16* __restrict__ kT,
    const u16* __restrict__ qT, const u16* __restrict__ vB,
    float* __restrict__ out) {
  __shared__ __align__(16) unsigned char smem[38912];

  int bid = blockIdx.x;
  int b = bid & 7;                  // XCD-local batch
  int sub = bid >> 3;               // 0..95
  int trip = sub / 3;
  int rem = sub - trip * 3;
  int tid = threadIdx.x;
  int wave = tid >> 6, lane = tid & 63;

  if (rem == 2) {
    // ========== conv: R10 body (Xc 16B-slot swizzled by row) ==========
    int ln = lane & 15, g = lane >> 4;
    u16* Xc = (u16*)smem;           // [4*34 rows][72], 19.6 KB
    int hp = trip >> 1, coh = trip & 1;
    int h0 = hp * 2;
    int co0 = coh * 128 + wave * 32;

    f32x4 acc[2][4];
#pragma unroll
    for (int i = 0; i < 2; ++i)
#pragma unroll
      for (int j = 0; j < 4; ++j) acc[i][j] = (f32x4){0.f, 0.f, 0.f, 0.f};

    {
      int rp = tid >> 6, rest = tid & 63;
      int which = rest >> 5, cp = rest & 31;
      *(unsigned*)&Xc[(rp * 34 + which * 33) * 72 + cp * 2] = 0u;
    }

    for (int c0 = 0; c0 < 256; c0 += 64) {
      __syncthreads();
#pragma unroll
      for (int rep = 0; rep < 4; ++rep) {
        int flat = rep * 256 + tid;
        int cg = flat & 7, w = (flat >> 3) & 31, rp = flat >> 8;
        int row = h0 - 1 + rp;
        short8 v = {0, 0, 0, 0, 0, 0, 0, 0};
        if ((unsigned)row < 32u)
          v = *(const short8*)&xT[(b * 1024 + row * 32 + w) * 256 + c0 + cg * 8];
        int rowS = rp * 34 + w + 1;
        *(short8*)&Xc[rowS * 72 + ((cg ^ (rowS & 7)) * 8)] = v;
      }
      __syncthreads();
#pragma unroll
      for (int ks = 0; ks < 2; ++ks) {
        int ko = c0 + ks * 32 + g * 8;
        int slot = ks * 4 + g;
#pragma unroll
        for (int r = 0; r < 3; ++r)
#pragma unroll
          for (int s = 0; s < 3; ++s) {
            int tap = r * 3 + s;
            short8 a0 = *(const short8*)&WcT[(tap * 256 + co0 + ln) * 256 + ko];
            short8 a1 =
                *(const short8*)&WcT[(tap * 256 + co0 + 16 + ln) * 256 + ko];
#pragma unroll
            for (int jt = 0; jt < 4; ++jt) {
              int rowp = ((jt >> 1) + r) * 34 + (jt & 1) * 16 + ln + s;
              short8 bf =
                  *(const short8*)&Xc[rowp * 72 + ((slot ^ (rowp & 7)) * 8)];
              acc[0][jt] = __builtin_amdgcn_mfma_f32_16x16x32_bf16(
                  a0, bf, acc[0][jt], 0, 0, 0);
              acc[1][jt] = __builtin_amdgcn_mfma_f32_16x16x32_bf16(
                  a1, bf, acc[1][jt], 0, 0, 0);
            }
          }
      }
    }

#pragma unroll
    for (int it = 0; it < 2; ++it)
#pragma unroll
      for (int r4 = 0; r4 < 4; ++r4) {
        int co = co0 + it * 16 + g * 4 + r4;
        float bias = cb[co];
#pragma unroll
        for (int jt = 0; jt < 4; ++jt) {
          int h = h0 + (jt >> 1), w = (jt & 1) * 16 + ln;
          out[((b * 512 + co) * 32 + h) * 32 + w] = acc[it][jt][r4] + bias;
        }
      }
    return;
  }

  // ===== attn: 32x32x16, in-register P, cross-iter pipeline (4 buffers) =====
  u16* kvb = (u16*)smem;                  // 4 buffers x 4864 u16
  int idx = trip * 2 + rem;               // 0..63
  int h = idx >> 3, qt = idx & 7;
  int nw = qt * 128 + wave * 32;
  int lq = lane & 31, hi = lane >> 5;

  const u16* kb = kT + (b * 8 + h) * (1024 * 32);
  const u16* qb = qT + (b * 8 + h) * (1024 * 32);
  const u16* vb = vB + (b * 256 + h * 32) * 1024;

  short8 qf0 = *(const short8*)&qb[(nw + lq) * 32 + hi * 8];
  short8 qf1 = *(const short8*)&qb[(nw + lq) * 32 + 16 + hi * 8];

  int sr = tid >> 2, ss = tid & 3;
  int dvr = tid >> 3, vs = tid & 7;
  const u16* ksrc = kb + sr * 32 + ss * 8;
  const u16* vsrc = vb + dvr * 1024 + vs * 8;
  int kdst = sr * 40 + ss * 8;
  int vdst = 2560 + dvr * 72 + vs * 8;

  int kr0 = lq * 40;
  int kr1 = (32 + lq) * 40;
  int vr = 2560 + lq * 72;

  f32x16 o0a = {}, o0b = {};
  float mx = -1e30f, l = 0.f;

  // prologue: tile 0 -> buf0; issue tile 1 loads; QK(0)
  short8 kp = *(const short8*)ksrc;
  short8 vp = *(const short8*)vsrc;
  *(short8*)&kvb[kdst] = kp;
  *(short8*)&kvb[vdst] = vp;
  kp = *(const short8*)(ksrc + 2048);
  vp = *(const short8*)(vsrc + 64);
  __syncthreads();

  f32x16 sc0 = {}, sc1 = {};
  {
    short8 ka00 = *(const short8*)&kvb[kr0 + hi * 8];
    short8 ka01 = *(const short8*)&kvb[kr0 + 16 + hi * 8];
    short8 ka10 = *(const short8*)&kvb[kr1 + hi * 8];
    short8 ka11 = *(const short8*)&kvb[kr1 + 16 + hi * 8];
    sc0 = __builtin_amdgcn_mfma_f32_32x32x16_bf16(ka00, qf0, sc0, 0, 0, 0);
    sc1 = __builtin_amdgcn_mfma_f32_32x32x16_bf16(ka10, qf0, sc1, 0, 0, 0);
    sc0 = __builtin_amdgcn_mfma_f32_32x32x16_bf16(ka01, qf1, sc0, 0, 0, 0);
    sc1 = __builtin_amdgcn_mfma_f32_32x32x16_bf16(ka11, qf1, sc1, 0, 0, 0);
  }

#pragma unroll 4
  for (int t = 0; t < 16; ++t) {
    u16* bn = kvb + ((t + 1) & 3) * 4864;        // tile t+1 buffer
    const u16* bcur = kvb + (t & 3) * 4864;      // tile t buffer (V source)
    if (t < 15) {
      *(short8*)&bn[kdst] = kp;
      *(short8*)&bn[vdst] = vp;
    }
    if (t < 14) {
      kp = *(const short8*)(ksrc + (t + 2) * 2048);
      vp = *(const short8*)(vsrc + (t + 2) * 64);
    }
    __syncthreads();

    // ---- QK^T(t+1): issued FIRST; LDS reads + MFMA latency hide under
    //      the softmax(t) VALU burst below (separate pipes). ----
    f32x16 sn0 = {}, sn1 = {};
    if (t < 15) {
      __builtin_amdgcn_s_setprio(1);
      short8 ka00 = *(const short8*)&bn[kr0 + hi * 8];
      short8 ka01 = *(const short8*)&bn[kr0 + 16 + hi * 8];
      short8 ka10 = *(const short8*)&bn[kr1 + hi * 8];
      short8 ka11 = *(const short8*)&bn[kr1 + 16 + hi * 8];
      sn0 = __builtin_amdgcn_mfma_f32_32x32x16_bf16(ka00, qf0, sn0, 0, 0, 0);
      sn1 = __builtin_amdgcn_mfma_f32_32x32x16_bf16(ka10, qf0, sn1, 0, 0, 0);
      sn0 = __builtin_amdgcn_mfma_f32_32x32x16_bf16(ka01, qf1, sn0, 0, 0, 0);
      sn1 = __builtin_amdgcn_mfma_f32_32x32x16_bf16(ka11, qf1, sn1, 0, 0, 0);
      __builtin_amdgcn_s_setprio(0);
    }

    // V fragments for PV(t), from tile-t buffer
    short8 vf0 = *(const short8*)&bcur[vr + hi * 8];
    short8 vf1 = *(const short8*)&bcur[vr + 16 + hi * 8];
    short8 vf2 = *(const short8*)&bcur[vr + 32 + hi * 8];
    short8 vf3 = *(const short8*)&bcur[vr + 48 + hi * 8];

    // ---- softmax(t) on sc (exp2 domain) ----
    float tmax = sc0[0];
#pragma unroll
    for (int r = 1; r < 16; ++r) tmax = fmaxf(tmax, sc0[r]);
#pragma unroll
    for (int r = 0; r < 16; ++r) tmax = fmaxf(tmax, sc1[r]);
    tmax = fmaxf(tmax, __shfl_xor(tmax, 32));

    if (!__all(tmax - mx <= 8.0f)) {
      float nm = fmaxf(mx, tmax);
      float sc = __builtin_amdgcn_exp2f(mx - nm);
#pragma unroll
      for (int r = 0; r < 16; ++r) {
        o0a[r] *= sc;
        o0b[r] *= sc;
      }
      l *= sc;
      mx = nm;
    }

#pragma unroll
    for (int r = 0; r < 16; ++r) {
      sc0[r] = __builtin_amdgcn_exp2f(sc0[r] - mx);
      sc1[r] = __builtin_amdgcn_exp2f(sc1[r] - mx);
    }
    float ts = 0.f;
#pragma unroll
    for (int r = 0; r < 16; ++r) ts += sc0[r] + sc1[r];
    ts += __shfl_xor(ts, 32);
    l += ts;

    // ---- PV(t) ----
    __builtin_amdgcn_s_setprio(1);
#define PV_CHUNK(SV, CB, VF, ACC)                                             \
  {                                                                           \
    unsigned A0 = packP(SV[(CB) + 0], SV[(CB) + 1]);                          \
    unsigned A1 = packP(SV[(CB) + 2], SV[(CB) + 3]);                          \
    unsigned B0 = packP(SV[(CB) + 4], SV[(CB) + 5]);                          \
    unsigned B1 = packP(SV[(CB) + 6], SV[(CB) + 7]);                          \
    unsigned sm0 = hi ? A0 : B0, sm1 = hi ? A1 : B1;                          \
    unsigned r0_ = (unsigned)__shfl_xor((int)sm0, 32);                        \
    unsigned r1_ = (unsigned)__shfl_xor((int)sm1, 32);                        \
    uint4 fw;                                                                 \
    fw.x = hi ? r0_ : A0;                                                     \
    fw.y = hi ? r1_ : A1;                                                     \
    fw.z = hi ? B0 : r0_;                                                     \
    fw.w = hi ? B1 : r1_;                                                     \
    short8 pf = __builtin_bit_cast(short8, fw);                               \
    ACC = __builtin_amdgcn_mfma_f32_32x32x16_bf16(VF, pf, ACC, 0, 0, 0);      \
  }
    PV_CHUNK(sc0, 0, vf0, o0a)
    PV_CHUNK(sc0, 8, vf1, o0b)
    PV_CHUNK(sc1, 0, vf2, o0a)
    PV_CHUNK(sc1, 8, vf3, o0b)
#undef PV_CHUNK
    __builtin_amdgcn_s_setprio(0);

    sc0 = sn0;
    sc1 = sn1;
  }

  float rl = 1.f / l;
  float* ob = out + (b * 512 + 256 + h * 32) * 1024 + nw + lq;
#pragma unroll
  for (int r = 0; r < 16; ++r) {
    int dv = (r & 3) + 8 * (r >> 2) + 4 * hi;
    ob[dv * 1024] = (o0a[r] + o0b[r]) * rl;
  }
}

// ---------------------------------------------------------------------------
extern "C" void kernel_launch(void* const* d_in, const int* in_sizes, int n_in,
                              void* d_out, int out_size, void* d_ws,
                              size_t ws_size, hipStream_t stream) {
  const float* x  = (const float*)d_in[0];
  const float* cw = (const float*)d_in[1];
  const float* cb = (const float*)d_in[2];
  const float* aw = (const float*)d_in[3];
  const float* ab = (const float*)d_in[4];
  float* out = (float*)d_out;

  char* ws = (char*)d_ws;
  u16* vB  = (u16*)ws;                           //  4,194,304 B
  u16* kT  = (u16*)(ws + 4194304);               //  4,194,304 B
  u16* qT  = (u16*)(ws + 8388608);               //  4,194,304 B
  u16* xT  = (u16*)(ws + 12582912);              //  4,194,304 B
  u16* WcT = (u16*)(ws + 16777216);              //  1,179,648 B
  u16* WaT = (u16*)(ws + 17956864);              //    393,216 B

  prep_kernel<<<320, 256, 0, stream>>>(x, cw, aw, xT, WcT, WaT);
  kqv_kernel<<<768, 256, 0, stream>>>(xT, WaT, ab, kT, qT, vB);
  conv_attn_kernel<<<768, 256, 0, stream>>>(xT, WcT, cb, kT, qT, vB, out);
}